// Round 8
// baseline (5522.981 us; speedup 1.0000x reference)
//
#include <hip/hip_runtime.h>
#include <hip/hip_bf16.h>
#include <stdint.h>

// B=128, T=25, V=10000, E=512, NF=2048, H=512, MAP=512, IN0=1024
// Round 13: row-split persistent GRU (round 12) with the repack bug fixed:
// repack_w copied uint2 (4 bf16) into an 8-bf16 fragment slot -> upper half
// garbage. Now uint4 (16B). No inter-block sync anywhere in the recurrence.

typedef __hip_bfloat16 bf16;
typedef __attribute__((ext_vector_type(8))) short frag8;   // 8 bf16 = 4 VGPR
typedef __attribute__((ext_vector_type(4))) float f32x4;

#define T_N 25

__device__ __forceinline__ float bf2f(bf16 x){ return __bfloat162float(x); }
__device__ __forceinline__ bf16 f2bf(float x){ return __float2bfloat16(x); }
__device__ __forceinline__ f32x4 mfma16(frag8 a, frag8 b, f32x4 c){
  return __builtin_amdgcn_mfma_f32_16x16x32_bf16(a, b, c, 0, 0, 0);
}
__device__ __forceinline__ void gld_lds16(const bf16* g, bf16* l){
  __builtin_amdgcn_global_load_lds((const __attribute__((address_space(1))) unsigned int*)g,
                                   (__attribute__((address_space(3))) unsigned int*)l, 16, 0, 0);
}
__device__ __forceinline__ float sigmoidf_(float x){ return 1.f/(1.f + __expf(-x)); }
__device__ __forceinline__ float tanhf_(float x){ return 2.f/(1.f + __expf(-2.f*x)) - 1.f; }

// ---------------- dtype detection ----------------
__global__ __launch_bounds__(256) void detect_kernel(const unsigned short* __restrict__ embu,
    const int* __restrict__ tok32, int* __restrict__ flags){
  __shared__ int cF, cT;
  if (threadIdx.x == 0){ cF = 0; cT = 0; }
  __syncthreads();
  int bad = 0;
  for (int j = threadIdx.x; j < 512; j += 256){
    unsigned e = (embu[2*j] >> 7) & 0xFFu;
    if (e > 160u) bad++;
  }
  if (bad) atomicAdd(&cF, bad);
  int nz = 0;
  for (int j = threadIdx.x; j < 128; j += 256)
    if (tok32[2*j + 1] != 0) nz++;
  if (nz) atomicAdd(&cT, nz);
  __syncthreads();
  if (threadIdx.x == 0){
    flags[0] = (cF > 8) ? 1 : 0;
    flags[1] = (cT < 4) ? 1 : 0;
  }
}

// ---------------- conversions ----------------
__global__ __launch_bounds__(256) void cvt_split(const void* __restrict__ src,
    bf16* __restrict__ hi, bf16* __restrict__ lo, int n, const int* __restrict__ flags){
  int i = (blockIdx.x*256 + threadIdx.x)*4;
  if (i >= n) return;
  bool isf = flags[0] != 0;
  #pragma unroll
  for (int j=0;j<4;j++){
    float x = isf ? ((const float*)src)[i+j] : bf2f(((const bf16*)src)[i+j]);
    bf16 h = f2bf(x);
    hi[i+j] = h;
    if (lo) lo[i+j] = f2bf(x - bf2f(h));
  }
}

struct CD { const void* src; float* dst; int n; };
struct CDs { CD d[8]; };
__global__ __launch_bounds__(256) void cvt_f32_batch(CDs all, const int* __restrict__ flags){
  CD d = all.d[blockIdx.y];
  int i = blockIdx.x*256 + threadIdx.x;
  if (i >= d.n) return;
  d.dst[i] = (flags[0] != 0) ? ((const float*)d.src)[i] : bf2f(((const bf16*)d.src)[i]);
}

// ---------------- transpose + split ----------------
struct TD { const void* src; bf16* dh; bf16* dl; int k0, Kd, Nd, Ns, NsV; };
struct TDs { TD d[14]; };
__global__ __launch_bounds__(256) void transpose_many(TDs all, const int* __restrict__ flags){
  TD d = all.d[blockIdx.y];
  int tilesN = d.Nd >> 5, tilesK = d.Kd >> 5;
  if ((int)blockIdx.x >= tilesN*tilesK) return;
  bool isf = flags[0] != 0;
  int tn = blockIdx.x % tilesN, tk = blockIdx.x / tilesN;
  int nt0 = tn*32, kt0 = tk*32;
  __shared__ float tile[32][33];
  int tx = threadIdx.x & 31, ty = threadIdx.x >> 5;
  #pragma unroll
  for (int p=0;p<4;p++){
    int k = kt0 + ty + p*8, n = nt0 + tx;
    float v = 0.f;
    if (n < d.NsV){
      size_t idx = (size_t)(d.k0 + k)*d.Ns + n;
      v = isf ? ((const float*)d.src)[idx] : bf2f(((const bf16*)d.src)[idx]);
    }
    tile[ty + p*8][tx] = v;
  }
  __syncthreads();
  #pragma unroll
  for (int p=0;p<4;p++){
    int n = nt0 + ty + p*8, k = kt0 + tx;
    float v = tile[tx][ty + p*8];
    bf16 h = f2bf(v);
    d.dh[(size_t)n*d.Kd + k] = h;
    if (d.dl) d.dl[(size_t)n*d.Kd + k] = f2bf(v - bf2f(h));
  }
}

// ---------------- weight repack into B-fragment order ----------------
// src [1536][512] (rows u|r|c) -> dst[g][nt][kc][lane][8]:
//   n = g*512 + nt*16 + (lane&15), k = kc*32 + (lane>>4)*8
struct RD { const bf16* s; bf16* d; };
struct RDs { RD d[4]; };
__global__ __launch_bounds__(256) void repack_w(RDs all){
  RD rd = all.d[blockIdx.y];
  int G = blockIdx.x*256 + threadIdx.x;       // 0..98303
  int l  = G & 63;
  int kc = (G >> 6) & 15;
  int nt = (G >> 10) & 31;
  int g  = G >> 15;                            // 0..2
  int n = g*512 + nt*16 + (l & 15);
  int k = kc*32 + ((l >> 4) << 3);
  *(uint4*)(rd.d + (size_t)G*8) = *(const uint4*)(rd.s + (size_t)n*512 + k);
}

// ---------------- split GEMM (batched pre/post passes) ----------------
template<int MODE>
__global__ __launch_bounds__(256) void gemm_split(
    const bf16* __restrict__ Ah, const bf16* __restrict__ Al,
    const bf16* __restrict__ Bth, const bf16* __restrict__ Btl,
    const float* __restrict__ bias, float* __restrict__ C,
    bf16* __restrict__ Ch, bf16* __restrict__ Cl, int K, int N)
{
  __shared__ bf16 Ash[128*32], Asl[128*32], Bsh[128*32], Bsl[128*32];
  const int m0 = blockIdx.y*128, n0 = blockIdx.x*128;
  const int tid = threadIdx.x, lane = tid & 63, wave = tid >> 6;
  const int wr = wave >> 1, wc = wave & 1, cl = lane & 15, cq = lane >> 4;
  f32x4 acc[4][4];
  #pragma unroll
  for (int i=0;i<4;i++)
    #pragma unroll
    for (int j=0;j<4;j++) acc[i][j] = (f32x4){0.f,0.f,0.f,0.f};

  const int r0 = tid >> 2, kc0 = (tid & 3)*8;
  for (int kt = 0; kt < K; kt += 32){
    gld_lds16(Ah  + (size_t)(m0 + r0)*K      + kt + kc0, Ash + (wave*64)*8);
    gld_lds16(Ah  + (size_t)(m0 + 64 + r0)*K + kt + kc0, Ash + (256 + wave*64)*8);
    gld_lds16(Al  + (size_t)(m0 + r0)*K      + kt + kc0, Asl + (wave*64)*8);
    gld_lds16(Al  + (size_t)(m0 + 64 + r0)*K + kt + kc0, Asl + (256 + wave*64)*8);
    gld_lds16(Bth + (size_t)(n0 + r0)*K      + kt + kc0, Bsh + (wave*64)*8);
    gld_lds16(Bth + (size_t)(n0 + 64 + r0)*K + kt + kc0, Bsh + (256 + wave*64)*8);
    gld_lds16(Btl + (size_t)(n0 + r0)*K      + kt + kc0, Bsl + (wave*64)*8);
    gld_lds16(Btl + (size_t)(n0 + 64 + r0)*K + kt + kc0, Bsl + (256 + wave*64)*8);
    __syncthreads();
    frag8 ah[4], al[4], bh[4], bl[4];
    #pragma unroll
    for (int i=0;i<4;i++){
      ah[i] = *(const frag8*)(Ash + (64*wr + 16*i + cl)*32 + cq*8);
      al[i] = *(const frag8*)(Asl + (64*wr + 16*i + cl)*32 + cq*8);
      bh[i] = *(const frag8*)(Bsh + (64*wc + 16*i + cl)*32 + cq*8);
      bl[i] = *(const frag8*)(Bsl + (64*wc + 16*i + cl)*32 + cq*8);
    }
    #pragma unroll
    for (int i=0;i<4;i++)
      #pragma unroll
      for (int j=0;j<4;j++){
        acc[i][j] = mfma16(ah[i], bh[j], acc[i][j]);
        acc[i][j] = mfma16(ah[i], bl[j], acc[i][j]);
        acc[i][j] = mfma16(al[i], bh[j], acc[i][j]);
      }
    __syncthreads();
  }
  #pragma unroll
  for (int j=0;j<4;j++){
    int col = n0 + 64*wc + 16*j + cl;
    float bv = bias[col];
    #pragma unroll
    for (int i=0;i<4;i++){
      int rowb = m0 + 64*wr + 16*i + cq*4;
      #pragma unroll
      for (int v=0;v<4;v++){
        float val = acc[i][j][v] + bv;
        int row = rowb + v;
        if (MODE == 1){
          val = (val > 0.f) ? val : 0.01f*val;
          bf16 h = f2bf(val);
          Ch[(size_t)row*N + col] = h;
          Cl[(size_t)row*N + col] = f2bf(val - bf2f(h));
        } else {
          C[(size_t)row*N + col] = val;
        }
      }
    }
  }
}

// ---------------- logits GEMM ----------------
__global__ __launch_bounds__(256) void gemm_logits(
    const bf16* __restrict__ A, const bf16* __restrict__ Bt,
    const float* __restrict__ bias, float* __restrict__ C, int K, int NV)
{
  __shared__ bf16 As[128*32];
  __shared__ bf16 Bs[128*32];
  const int m0 = blockIdx.y*128, n0 = blockIdx.x*128;
  const int tid = threadIdx.x, lane = tid & 63, wave = tid >> 6;
  const int wr = wave >> 1, wc = wave & 1, cl = lane & 15, cq = lane >> 4;
  f32x4 acc[4][4];
  #pragma unroll
  for (int i=0;i<4;i++)
    #pragma unroll
    for (int j=0;j<4;j++) acc[i][j] = (f32x4){0.f,0.f,0.f,0.f};
  const int r0 = tid >> 2, kc0 = (tid & 3)*8;
  for (int kt = 0; kt < K; kt += 32){
    gld_lds16(A  + (size_t)(m0 + r0)*K      + kt + kc0, As + (wave*64)*8);
    gld_lds16(A  + (size_t)(m0 + 64 + r0)*K + kt + kc0, As + (256 + wave*64)*8);
    gld_lds16(Bt + (size_t)(n0 + r0)*K      + kt + kc0, Bs + (wave*64)*8);
    gld_lds16(Bt + (size_t)(n0 + 64 + r0)*K + kt + kc0, Bs + (256 + wave*64)*8);
    __syncthreads();
    frag8 af[4], bfr[4];
    #pragma unroll
    for (int i=0;i<4;i++){
      af[i]  = *(const frag8*)(As + (64*wr + 16*i + cl)*32 + cq*8);
      bfr[i] = *(const frag8*)(Bs + (64*wc + 16*i + cl)*32 + cq*8);
    }
    #pragma unroll
    for (int i=0;i<4;i++)
      #pragma unroll
      for (int j=0;j<4;j++)
        acc[i][j] = mfma16(af[i], bfr[j], acc[i][j]);
    __syncthreads();
  }
  #pragma unroll
  for (int j=0;j<4;j++){
    int col = n0 + 64*wc + 16*j + cl;
    if (col >= NV) continue;
    float bv = bias[col];
    #pragma unroll
    for (int i=0;i<4;i++){
      int rowb = m0 + 64*wr + 16*i + cq*4;
      #pragma unroll
      for (int v=0;v<4;v++){
        int row = rowb + v;
        int b = row & 127, t = row >> 7;
        C[((size_t)b*T_N + t)*NV + col] = acc[i][j][v] + bv;
      }
    }
  }
}

// ---------------- X0A build ----------------
__global__ __launch_bounds__(256) void build_x0a(const int* __restrict__ tok32,
    const bf16* __restrict__ embH, const bf16* __restrict__ embL,
    const bf16* __restrict__ pH, const bf16* __restrict__ pL,
    bf16* __restrict__ XH, bf16* __restrict__ XL, const int* __restrict__ flags)
{
  int r = blockIdx.x;
  int t = r >> 7, b = r & 127;
  int idx = b*T_N + t;
  int tok = (flags[1] != 0) ? tok32[2*idx] : tok32[idx];
  int k = threadIdx.x * 4;
  uint2 hv, lv;
  if (k < 512){
    hv = *(const uint2*)(embH + (size_t)tok*512 + k);
    lv = *(const uint2*)(embL + (size_t)tok*512 + k);
  } else {
    hv = *(const uint2*)(pH + b*512 + (k - 512));
    lv = *(const uint2*)(pL + b*512 + (k - 512));
  }
  *(uint2*)(XH + (size_t)r*1024 + k) = hv;
  *(uint2*)(XL + (size_t)r*1024 + k) = lv;
}

// ================= row-split persistent GRU layer =================
// 8 blocks x 256 threads. Block b owns batch rows [b*16, b*16+16).
// h in block-local LDS (bf16 hi/lo, A-frag layout, XOR-swizzled) + registers.
// Weights streamed from packed global layout (coalesced; L2-resident).

// A-fragment read: element (row=lane&15, k=kc*32+(lane>>4)*8 ..+8)
__device__ __forceinline__ frag8 lds_afrag(const bf16* buf, int lane, int kc){
  int byte = ((lane & 15) << 10) + (kc << 6) + ((lane >> 4) << 4);
  byte ^= (lane & 7) << 4;                      // bank swizzle (G4)
  return *(const frag8*)((const char*)buf + byte);
}
// write element (row, col) with matching swizzle
__device__ __forceinline__ void lds_wr(bf16* buf, int row, int col, bf16 v){
  int byte = (row << 10) + ((col << 1) ^ ((row & 7) << 4));
  *(bf16*)((char*)buf + byte) = v;
}

__global__ __launch_bounds__(256, 1) void gru_layer(
    const bf16* __restrict__ Wph, const bf16* __restrict__ Wpl, // packed [3][32][16][64][8]
    const float* __restrict__ Xall,                             // [3200][1536]
    float* __restrict__ hf,                                     // [128][512]
    bf16* __restrict__ Hh, bf16* __restrict__ Hl)               // [3200][512]
{
  __shared__ bf16 hA_h[8192], hA_l[8192];       // h state, A-layout
  __shared__ bf16 rA_h[8192], rA_l[8192];       // r*h, A-layout
  const int tid = threadIdx.x, lane = tid & 63, wave = tid >> 6;
  const int cl = lane & 15, cq = lane >> 4;
  const int r0 = blockIdx.x * 16;               // global batch-row base

  for (int i = tid*8; i < 8192; i += 2048){
    *(uint4*)(hA_h + i) = (uint4){0,0,0,0};
    *(uint4*)(hA_l + i) = (uint4){0,0,0,0};
  }
  __syncthreads();

  float hold[8][4], ureg[8][4];
  #pragma unroll
  for (int jt=0;jt<8;jt++)
    #pragma unroll
    for (int v=0;v<4;v++) hold[jt][v] = 0.f;

  #pragma unroll 1
  for (int t = 0; t < T_N; t++){
    // ---- phase A: u = sig(h@Wu + Xu); rh = sig(h@Wr + Xr)*h ----
    float xu[8][4], xr[8][4];
    #pragma unroll
    for (int jt=0;jt<8;jt++)
      #pragma unroll
      for (int v=0;v<4;v++){
        size_t xrow = (size_t)(t*128 + r0 + cq*4 + v) * 1536;
        int col = wave*128 + jt*16 + cl;
        xu[jt][v] = Xall[xrow + col];
        xr[jt][v] = Xall[xrow + 512 + col];
      }
    f32x4 aU[8], aR[8];
    #pragma unroll
    for (int jt=0;jt<8;jt++){ aU[jt] = (f32x4){0.f,0.f,0.f,0.f}; aR[jt] = (f32x4){0.f,0.f,0.f,0.f}; }
    #pragma unroll
    for (int kc=0;kc<16;kc++){
      frag8 AH = lds_afrag(hA_h, lane, kc);
      frag8 AL = lds_afrag(hA_l, lane, kc);
      #pragma unroll
      for (int jt=0;jt<8;jt++){
        int nt = wave*8 + jt;
        size_t bu = (((size_t)(nt)*16 + kc)*64 + lane)*8;          // g=0 (u)
        size_t br = (((size_t)(32 + nt)*16 + kc)*64 + lane)*8;     // g=1 (r)
        frag8 wuh = *(const frag8*)(Wph + bu);
        frag8 wul = *(const frag8*)(Wpl + bu);
        frag8 wrh = *(const frag8*)(Wph + br);
        frag8 wrl = *(const frag8*)(Wpl + br);
        aU[jt] = mfma16(AH, wuh, aU[jt]);
        aU[jt] = mfma16(AH, wul, aU[jt]);
        aU[jt] = mfma16(AL, wuh, aU[jt]);
        aR[jt] = mfma16(AH, wrh, aR[jt]);
        aR[jt] = mfma16(AH, wrl, aR[jt]);
        aR[jt] = mfma16(AL, wrh, aR[jt]);
      }
    }
    #pragma unroll
    for (int jt=0;jt<8;jt++)
      #pragma unroll
      for (int v=0;v<4;v++){
        int row = cq*4 + v, col = wave*128 + jt*16 + cl;
        float u = sigmoidf_(aU[jt][v] + xu[jt][v]);
        ureg[jt][v] = u;
        float rh = sigmoidf_(aR[jt][v] + xr[jt][v]) * hold[jt][v];
        bf16 hh = f2bf(rh);
        lds_wr(rA_h, row, col, hh);
        lds_wr(rA_l, row, col, f2bf(rh - bf2f(hh)));
      }
    __syncthreads();

    // ---- phase B: h' = u*h + (1-u)*tanh((r*h)@Wc + Xc) ----
    float xc[8][4];
    #pragma unroll
    for (int jt=0;jt<8;jt++)
      #pragma unroll
      for (int v=0;v<4;v++){
        size_t xrow = (size_t)(t*128 + r0 + cq*4 + v) * 1536;
        xc[jt][v] = Xall[xrow + 1024 + wave*128 + jt*16 + cl];
      }
    f32x4 aC[8];
    #pragma unroll
    for (int jt=0;jt<8;jt++) aC[jt] = (f32x4){0.f,0.f,0.f,0.f};
    #pragma unroll
    for (int kc=0;kc<16;kc++){
      frag8 AH = lds_afrag(rA_h, lane, kc);
      frag8 AL = lds_afrag(rA_l, lane, kc);
      #pragma unroll
      for (int jt=0;jt<8;jt++){
        int nt = wave*8 + jt;
        size_t bc = (((size_t)(64 + nt)*16 + kc)*64 + lane)*8;     // g=2 (c)
        frag8 wch = *(const frag8*)(Wph + bc);
        frag8 wcl = *(const frag8*)(Wpl + bc);
        aC[jt] = mfma16(AH, wch, aC[jt]);
        aC[jt] = mfma16(AH, wcl, aC[jt]);
        aC[jt] = mfma16(AL, wch, aC[jt]);
      }
    }
    #pragma unroll
    for (int jt=0;jt<8;jt++)
      #pragma unroll
      for (int v=0;v<4;v++){
        int row = cq*4 + v, col = wave*128 + jt*16 + cl;
        float hh = tanhf_(aC[jt][v] + xc[jt][v]);
        float u = ureg[jt][v];
        float hn = u*hold[jt][v] + (1.f - u)*hh;
        hold[jt][v] = hn;
        bf16 hhi = f2bf(hn), hlo = f2bf(hn - bf2f(hhi));
        lds_wr(hA_h, row, col, hhi);
        lds_wr(hA_l, row, col, hlo);
        size_t ot = (size_t)(t*128 + r0 + row)*512 + col;
        Hh[ot] = hhi; Hl[ot] = hlo;
        if (t == T_N-1) hf[(size_t)(r0 + row)*512 + col] = hn;
      }
    __syncthreads();
  }
}

// ---------------- hidden output (f32) ----------------
__global__ __launch_bounds__(256) void hidden_out(const float* __restrict__ h0f,
    const float* __restrict__ h1f, float* __restrict__ out){
  int i = blockIdx.x*256 + threadIdx.x;
  out[i] = (i < 65536) ? h0f[i] : h1f[i - 65536];
}

// ---------------- host ----------------
extern "C" void kernel_launch(void* const* d_in, const int* in_sizes, int n_in,
                              void* d_out, int out_size, void* d_ws, size_t ws_size,
                              hipStream_t stream)
{
  const void* tokens = d_in[0];
  const void* cnn  = d_in[1];
  const void* emb  = d_in[2];
  const void* Win  = d_in[3];
  const void* bin  = d_in[4];
  const void* Wout = d_in[5];
  const void* bout = d_in[6];
  const void* Wu0  = d_in[7];
  const void* bu0  = d_in[8];
  const void* Wr0  = d_in[9];
  const void* br0  = d_in[10];
  const void* Wc0  = d_in[11];
  const void* bc0  = d_in[12];
  const void* Wu1  = d_in[13];
  const void* bu1  = d_in[14];
  const void* Wr1  = d_in[15];
  const void* br1  = d_in[16];
  const void* Wc1  = d_in[17];
  const void* bc1  = d_in[18];

  char* wp = (char*)d_ws;
  auto alloc = [&](size_t bytes) -> char* {
    char* r = wp; wp += (bytes + 255) & ~(size_t)255; return r;
  };
  auto B2 = [](size_t n){ return n*2; };
  bf16* WinTh  = (bf16*)alloc(B2(512*2048)); bf16* WinTl  = (bf16*)alloc(B2(512*2048));
  bf16* WoutTh = (bf16*)alloc(B2((size_t)10112*512));
  bf16* W0xTh = (bf16*)alloc(B2((size_t)1536*1024)); bf16* W0xTl = (bf16*)alloc(B2((size_t)1536*1024));
  bf16* W0hTh = (bf16*)alloc(B2((size_t)1536*512));  bf16* W0hTl = (bf16*)alloc(B2((size_t)1536*512));
  bf16* W1xTh = (bf16*)alloc(B2((size_t)1536*512));  bf16* W1xTl = (bf16*)alloc(B2((size_t)1536*512));
  bf16* W1hTh = (bf16*)alloc(B2((size_t)1536*512));  bf16* W1hTl = (bf16*)alloc(B2((size_t)1536*512));
  bf16* Wp0h = (bf16*)alloc(B2((size_t)1536*512));   bf16* Wp0l = (bf16*)alloc(B2((size_t)1536*512));
  bf16* Wp1h = (bf16*)alloc(B2((size_t)1536*512));   bf16* Wp1l = (bf16*)alloc(B2((size_t)1536*512));
  bf16* embH = (bf16*)alloc(B2((size_t)10000*512));
  bf16* embL = (bf16*)alloc(B2((size_t)10000*512));
  bf16* cnnH = (bf16*)alloc(B2(128*2048)); bf16* cnnL = (bf16*)alloc(B2(128*2048));
  bf16* pH   = (bf16*)alloc(B2(128*512)); bf16* pL = (bf16*)alloc(B2(128*512));
  bf16* X0AH = (bf16*)alloc(B2((size_t)3200*1024)); bf16* X0AL = (bf16*)alloc(B2((size_t)3200*1024));
  float* Xall = (float*)alloc((size_t)3200*1536*4);
  bf16* H0h = (bf16*)alloc(B2((size_t)3200*512)); bf16* H0l = (bf16*)alloc(B2((size_t)3200*512));
  bf16* H1h = (bf16*)alloc(B2((size_t)3200*512)); bf16* H1l = (bf16*)alloc(B2((size_t)3200*512));
  float* binF = (float*)alloc(512*4);
  float* boutF = (float*)alloc(10000*4);
  float* b0all = (float*)alloc(1536*4);
  float* b1all = (float*)alloc(1536*4);
  float* h0f = (float*)alloc(65536*4); float* h1f = (float*)alloc(65536*4);
  int* flags = (int*)alloc(256);

  detect_kernel<<<1, 256, 0, stream>>>((const unsigned short*)emb, (const int*)tokens, flags);
  cvt_split<<<5000, 256, 0, stream>>>(emb, embH, embL, 5120000, flags);
  cvt_split<<<256, 256, 0, stream>>>(cnn, cnnH, cnnL, 262144, flags);
  CDs cds;
  cds.d[0] = {bin,  binF,  512};
  cds.d[1] = {bout, boutF, 10000};
  cds.d[2] = {bu0,  b0all + 0,    512};
  cds.d[3] = {br0,  b0all + 512,  512};
  cds.d[4] = {bc0,  b0all + 1024, 512};
  cds.d[5] = {bu1,  b1all + 0,    512};
  cds.d[6] = {br1,  b1all + 512,  512};
  cds.d[7] = {bc1,  b1all + 1024, 512};
  cvt_f32_batch<<<dim3(40, 8), 256, 0, stream>>>(cds, flags);

  TDs tds;
  tds.d[0]  = {Win,  WinTh, WinTl, 0, 2048, 512, 512, 512};
  tds.d[1]  = {Wout, WoutTh, nullptr, 0, 512, 10112, 10000, 10000};
  tds.d[2]  = {Wu0, W0xTh,               W0xTl,               0,    1024, 512, 512, 512};
  tds.d[3]  = {Wr0, W0xTh + 512*1024,    W0xTl + 512*1024,    0,    1024, 512, 512, 512};
  tds.d[4]  = {Wc0, W0xTh + 1024*1024,   W0xTl + 1024*1024,   512,  1024, 512, 512, 512};
  tds.d[5]  = {Wu0, W0hTh,               W0hTl,               1024, 512,  512, 512, 512};
  tds.d[6]  = {Wr0, W0hTh + 512*512,     W0hTl + 512*512,     1024, 512,  512, 512, 512};
  tds.d[7]  = {Wc0, W0hTh + 1024*512,    W0hTl + 1024*512,    0,    512,  512, 512, 512};
  tds.d[8]  = {Wu1, W1xTh,               W1xTl,               0,    512,  512, 512, 512};
  tds.d[9]  = {Wr1, W1xTh + 512*512,     W1xTl + 512*512,     0,    512,  512, 512, 512};
  tds.d[10] = {Wc1, W1xTh + 1024*512,    W1xTl + 1024*512,    512,  512,  512, 512, 512};
  tds.d[11] = {Wu1, W1hTh,               W1hTl,               512,  512,  512, 512, 512};
  tds.d[12] = {Wr1, W1hTh + 512*512,     W1hTl + 512*512,     512,  512,  512, 512, 512};
  tds.d[13] = {Wc1, W1hTh + 1024*512,    W1hTl + 1024*512,    0,    512,  512, 512, 512};
  transpose_many<<<dim3(5056, 14), 256, 0, stream>>>(tds, flags);

  RDs rds;
  rds.d[0] = {W0hTh, Wp0h};
  rds.d[1] = {W0hTl, Wp0l};
  rds.d[2] = {W1hTh, Wp1h};
  rds.d[3] = {W1hTl, Wp1l};
  repack_w<<<dim3(384, 4), 256, 0, stream>>>(rds);

  gemm_split<1><<<dim3(4, 1), 256, 0, stream>>>(
      cnnH, cnnL, WinTh, WinTl, binF, nullptr, pH, pL, 2048, 512);
  build_x0a<<<3200, 256, 0, stream>>>((const int*)tokens, embH, embL, pH, pL, X0AH, X0AL, flags);
  gemm_split<0><<<dim3(12, 25), 256, 0, stream>>>(
      X0AH, X0AL, W0xTh, W0xTl, b0all, Xall, nullptr, nullptr, 1024, 1536);

  gru_layer<<<8, 256, 0, stream>>>(Wp0h, Wp0l, Xall, h0f, H0h, H0l);

  gemm_split<0><<<dim3(12, 25), 256, 0, stream>>>(
      H0h, H0l, W1xTh, W1xTl, b1all, Xall, nullptr, nullptr, 512, 1536);

  gru_layer<<<8, 256, 0, stream>>>(Wp1h, Wp1l, Xall, h1f, H1h, H1l);

  float* out = (float*)d_out;
  gemm_logits<<<dim3(79, 25), 256, 0, stream>>>(H1h, WoutTh, boutF, out, 512, 10000);
  hidden_out<<<512, 256, 0, stream>>>(h0f, h1f, out + 32000000);
}

// Round 9
// 1166.055 us; speedup vs baseline: 4.7365x; 4.7365x over previous
//
#include <hip/hip_runtime.h>
#include <hip/hip_bf16.h>
#include <stdint.h>

// B=128, T=25, V=10000, E=512, NF=2048, H=512, MAP=512, IN0=1024
// Round 14: hybrid row x col split GRU. 256 one-wave blocks = 8 row-groups x
// 32 col-blocks. Weights (16-col slice of u,r,c; hi+lo = 96KB) LDS-resident.
// h / r*h exchanged as (hi,lo)-packed uint32 via relaxed AGENT-scope atomics
// (coherent at L3, compiler-generated — no fences, no hand asm). Per-row-group
// flag/epoch barrier, bounded spins. u and h_old carried in registers.

typedef __hip_bfloat16 bf16;
typedef __attribute__((ext_vector_type(8))) short frag8;   // 8 bf16 = 4 VGPR
typedef __attribute__((ext_vector_type(4))) float f32x4;
typedef unsigned int u32;

#define T_N 25

__device__ __forceinline__ float bf2f(bf16 x){ return __bfloat162float(x); }
__device__ __forceinline__ bf16 f2bf(float x){ return __float2bfloat16(x); }
__device__ __forceinline__ f32x4 mfma16(frag8 a, frag8 b, f32x4 c){
  return __builtin_amdgcn_mfma_f32_16x16x32_bf16(a, b, c, 0, 0, 0);
}
__device__ __forceinline__ void gld_lds16(const bf16* g, bf16* l){
  __builtin_amdgcn_global_load_lds((const __attribute__((address_space(1))) unsigned int*)g,
                                   (__attribute__((address_space(3))) unsigned int*)l, 16, 0, 0);
}
__device__ __forceinline__ float sigmoidf_(float x){ return 1.f/(1.f + __expf(-x)); }
__device__ __forceinline__ float tanhf_(float x){ return 2.f/(1.f + __expf(-2.f*x)) - 1.f; }

// relaxed agent-scope atomics (coherent across XCDs, no fences)
__device__ __forceinline__ int ald(const int* p){
  return __hip_atomic_load(p, __ATOMIC_RELAXED, __HIP_MEMORY_SCOPE_AGENT);
}
__device__ __forceinline__ void ast(int* p, int v){
  __hip_atomic_store(p, v, __ATOMIC_RELAXED, __HIP_MEMORY_SCOPE_AGENT);
}
__device__ __forceinline__ u32 aldu(const u32* p){
  return __hip_atomic_load(p, __ATOMIC_RELAXED, __HIP_MEMORY_SCOPE_AGENT);
}
__device__ __forceinline__ void astu(u32* p, u32 v){
  __hip_atomic_store(p, v, __ATOMIC_RELAXED, __HIP_MEMORY_SCOPE_AGENT);
}

// ---------------- dtype detection ----------------
__global__ __launch_bounds__(256) void detect_kernel(const unsigned short* __restrict__ embu,
    const int* __restrict__ tok32, int* __restrict__ flags){
  __shared__ int cF, cT;
  if (threadIdx.x == 0){ cF = 0; cT = 0; }
  __syncthreads();
  int bad = 0;
  for (int j = threadIdx.x; j < 512; j += 256){
    unsigned e = (embu[2*j] >> 7) & 0xFFu;
    if (e > 160u) bad++;
  }
  if (bad) atomicAdd(&cF, bad);
  int nz = 0;
  for (int j = threadIdx.x; j < 128; j += 256)
    if (tok32[2*j + 1] != 0) nz++;
  if (nz) atomicAdd(&cT, nz);
  __syncthreads();
  if (threadIdx.x == 0){
    flags[0] = (cF > 8) ? 1 : 0;
    flags[1] = (cT < 4) ? 1 : 0;
  }
}

// ---------------- conversions ----------------
__global__ __launch_bounds__(256) void cvt_split(const void* __restrict__ src,
    bf16* __restrict__ hi, bf16* __restrict__ lo, int n, const int* __restrict__ flags){
  int i = (blockIdx.x*256 + threadIdx.x)*4;
  if (i >= n) return;
  bool isf = flags[0] != 0;
  #pragma unroll
  for (int j=0;j<4;j++){
    float x = isf ? ((const float*)src)[i+j] : bf2f(((const bf16*)src)[i+j]);
    bf16 h = f2bf(x);
    hi[i+j] = h;
    if (lo) lo[i+j] = f2bf(x - bf2f(h));
  }
}

struct CD { const void* src; float* dst; int n; };
struct CDs { CD d[8]; };
__global__ __launch_bounds__(256) void cvt_f32_batch(CDs all, const int* __restrict__ flags){
  CD d = all.d[blockIdx.y];
  int i = blockIdx.x*256 + threadIdx.x;
  if (i >= d.n) return;
  d.dst[i] = (flags[0] != 0) ? ((const float*)d.src)[i] : bf2f(((const bf16*)d.src)[i]);
}

// ---------------- init ----------------
__global__ __launch_bounds__(256) void init_zero(float* h0f, float* h1f,
    u32* Hp0, u32* Hp1, int* bar){
  int i = blockIdx.x*256 + threadIdx.x;       // grid 256 -> 65536
  if (i < 544) bar[i] = 0;
  if (i < 65536){
    h0f[i] = 0.f; h1f[i] = 0.f;
    Hp0[i] = 0u; Hp1[i] = 0u;
  }
}

// ---------------- transpose + split ----------------
struct TD { const void* src; bf16* dh; bf16* dl; int k0, Kd, Nd, Ns, NsV; };
struct TDs { TD d[14]; };
__global__ __launch_bounds__(256) void transpose_many(TDs all, const int* __restrict__ flags){
  TD d = all.d[blockIdx.y];
  int tilesN = d.Nd >> 5, tilesK = d.Kd >> 5;
  if ((int)blockIdx.x >= tilesN*tilesK) return;
  bool isf = flags[0] != 0;
  int tn = blockIdx.x % tilesN, tk = blockIdx.x / tilesN;
  int nt0 = tn*32, kt0 = tk*32;
  __shared__ float tile[32][33];
  int tx = threadIdx.x & 31, ty = threadIdx.x >> 5;
  #pragma unroll
  for (int p=0;p<4;p++){
    int k = kt0 + ty + p*8, n = nt0 + tx;
    float v = 0.f;
    if (n < d.NsV){
      size_t idx = (size_t)(d.k0 + k)*d.Ns + n;
      v = isf ? ((const float*)d.src)[idx] : bf2f(((const bf16*)d.src)[idx]);
    }
    tile[ty + p*8][tx] = v;
  }
  __syncthreads();
  #pragma unroll
  for (int p=0;p<4;p++){
    int n = nt0 + ty + p*8, k = kt0 + tx;
    float v = tile[tx][ty + p*8];
    bf16 h = f2bf(v);
    d.dh[(size_t)n*d.Kd + k] = h;
    if (d.dl) d.dl[(size_t)n*d.Kd + k] = f2bf(v - bf2f(h));
  }
}

// ---------------- split GEMM (batched pre/post passes) ----------------
template<int MODE>
__global__ __launch_bounds__(256) void gemm_split(
    const bf16* __restrict__ Ah, const bf16* __restrict__ Al,
    const bf16* __restrict__ Bth, const bf16* __restrict__ Btl,
    const float* __restrict__ bias, float* __restrict__ C,
    bf16* __restrict__ Ch, bf16* __restrict__ Cl, int K, int N)
{
  __shared__ bf16 Ash[128*32], Asl[128*32], Bsh[128*32], Bsl[128*32];
  const int m0 = blockIdx.y*128, n0 = blockIdx.x*128;
  const int tid = threadIdx.x, lane = tid & 63, wave = tid >> 6;
  const int wr = wave >> 1, wc = wave & 1, cl = lane & 15, cq = lane >> 4;
  f32x4 acc[4][4];
  #pragma unroll
  for (int i=0;i<4;i++)
    #pragma unroll
    for (int j=0;j<4;j++) acc[i][j] = (f32x4){0.f,0.f,0.f,0.f};

  const int r0 = tid >> 2, kc0 = (tid & 3)*8;
  for (int kt = 0; kt < K; kt += 32){
    gld_lds16(Ah  + (size_t)(m0 + r0)*K      + kt + kc0, Ash + (wave*64)*8);
    gld_lds16(Ah  + (size_t)(m0 + 64 + r0)*K + kt + kc0, Ash + (256 + wave*64)*8);
    gld_lds16(Al  + (size_t)(m0 + r0)*K      + kt + kc0, Asl + (wave*64)*8);
    gld_lds16(Al  + (size_t)(m0 + 64 + r0)*K + kt + kc0, Asl + (256 + wave*64)*8);
    gld_lds16(Bth + (size_t)(n0 + r0)*K      + kt + kc0, Bsh + (wave*64)*8);
    gld_lds16(Bth + (size_t)(n0 + 64 + r0)*K + kt + kc0, Bsh + (256 + wave*64)*8);
    gld_lds16(Btl + (size_t)(n0 + r0)*K      + kt + kc0, Bsl + (wave*64)*8);
    gld_lds16(Btl + (size_t)(n0 + 64 + r0)*K + kt + kc0, Bsl + (256 + wave*64)*8);
    __syncthreads();
    frag8 ah[4], al[4], bh[4], bl[4];
    #pragma unroll
    for (int i=0;i<4;i++){
      ah[i] = *(const frag8*)(Ash + (64*wr + 16*i + cl)*32 + cq*8);
      al[i] = *(const frag8*)(Asl + (64*wr + 16*i + cl)*32 + cq*8);
      bh[i] = *(const frag8*)(Bsh + (64*wc + 16*i + cl)*32 + cq*8);
      bl[i] = *(const frag8*)(Bsl + (64*wc + 16*i + cl)*32 + cq*8);
    }
    #pragma unroll
    for (int i=0;i<4;i++)
      #pragma unroll
      for (int j=0;j<4;j++){
        acc[i][j] = mfma16(ah[i], bh[j], acc[i][j]);
        acc[i][j] = mfma16(ah[i], bl[j], acc[i][j]);
        acc[i][j] = mfma16(al[i], bh[j], acc[i][j]);
      }
    __syncthreads();
  }
  #pragma unroll
  for (int j=0;j<4;j++){
    int col = n0 + 64*wc + 16*j + cl;
    float bv = bias[col];
    #pragma unroll
    for (int i=0;i<4;i++){
      int rowb = m0 + 64*wr + 16*i + cq*4;
      #pragma unroll
      for (int v=0;v<4;v++){
        float val = acc[i][j][v] + bv;
        int row = rowb + v;
        if (MODE == 1){
          val = (val > 0.f) ? val : 0.01f*val;
          bf16 h = f2bf(val);
          Ch[(size_t)row*N + col] = h;
          Cl[(size_t)row*N + col] = f2bf(val - bf2f(h));
        } else {
          C[(size_t)row*N + col] = val;
        }
      }
    }
  }
}

// ---------------- logits GEMM ----------------
__global__ __launch_bounds__(256) void gemm_logits(
    const bf16* __restrict__ A, const bf16* __restrict__ Bt,
    const float* __restrict__ bias, float* __restrict__ C, int K, int NV)
{
  __shared__ bf16 As[128*32];
  __shared__ bf16 Bs[128*32];
  const int m0 = blockIdx.y*128, n0 = blockIdx.x*128;
  const int tid = threadIdx.x, lane = tid & 63, wave = tid >> 6;
  const int wr = wave >> 1, wc = wave & 1, cl = lane & 15, cq = lane >> 4;
  f32x4 acc[4][4];
  #pragma unroll
  for (int i=0;i<4;i++)
    #pragma unroll
    for (int j=0;j<4;j++) acc[i][j] = (f32x4){0.f,0.f,0.f,0.f};
  const int r0 = tid >> 2, kc0 = (tid & 3)*8;
  for (int kt = 0; kt < K; kt += 32){
    gld_lds16(A  + (size_t)(m0 + r0)*K      + kt + kc0, As + (wave*64)*8);
    gld_lds16(A  + (size_t)(m0 + 64 + r0)*K + kt + kc0, As + (256 + wave*64)*8);
    gld_lds16(Bt + (size_t)(n0 + r0)*K      + kt + kc0, Bs + (wave*64)*8);
    gld_lds16(Bt + (size_t)(n0 + 64 + r0)*K + kt + kc0, Bs + (256 + wave*64)*8);
    __syncthreads();
    frag8 af[4], bfr[4];
    #pragma unroll
    for (int i=0;i<4;i++){
      af[i]  = *(const frag8*)(As + (64*wr + 16*i + cl)*32 + cq*8);
      bfr[i] = *(const frag8*)(Bs + (64*wc + 16*i + cl)*32 + cq*8);
    }
    #pragma unroll
    for (int i=0;i<4;i++)
      #pragma unroll
      for (int j=0;j<4;j++)
        acc[i][j] = mfma16(af[i], bfr[j], acc[i][j]);
    __syncthreads();
  }
  #pragma unroll
  for (int j=0;j<4;j++){
    int col = n0 + 64*wc + 16*j + cl;
    if (col >= NV) continue;
    float bv = bias[col];
    #pragma unroll
    for (int i=0;i<4;i++){
      int rowb = m0 + 64*wr + 16*i + cq*4;
      #pragma unroll
      for (int v=0;v<4;v++){
        int row = rowb + v;
        int b = row & 127, t = row >> 7;
        C[((size_t)b*T_N + t)*NV + col] = acc[i][j][v] + bv;
      }
    }
  }
}

// ---------------- X0A build ----------------
__global__ __launch_bounds__(256) void build_x0a(const int* __restrict__ tok32,
    const bf16* __restrict__ embH, const bf16* __restrict__ embL,
    const bf16* __restrict__ pH, const bf16* __restrict__ pL,
    bf16* __restrict__ XH, bf16* __restrict__ XL, const int* __restrict__ flags)
{
  int r = blockIdx.x;
  int t = r >> 7, b = r & 127;
  int idx = b*T_N + t;
  int tok = (flags[1] != 0) ? tok32[2*idx] : tok32[idx];
  int k = threadIdx.x * 4;
  uint2 hv, lv;
  if (k < 512){
    hv = *(const uint2*)(embH + (size_t)tok*512 + k);
    lv = *(const uint2*)(embL + (size_t)tok*512 + k);
  } else {
    hv = *(const uint2*)(pH + b*512 + (k - 512));
    lv = *(const uint2*)(pL + b*512 + (k - 512));
  }
  *(uint2*)(XH + (size_t)r*1024 + k) = hv;
  *(uint2*)(XL + (size_t)r*1024 + k) = lv;
}

// ================= hybrid row x col split persistent GRU =================
// 256 blocks x 64 threads. Block = (g = blk>>5 row-group, c = blk&31 col-slice).
// Owns output tile rows [16g,16g+16) x cols [16c,16c+16). Weights in LDS.
// Exchange via packed uint32 agent atomics; per-group epoch barrier.

// per-group epoch wait. master (c==0) aggregates 32 member flags, publishes.
__device__ __forceinline__ void wait_group(int* flg, int* gready, int g, int c,
                                           int lane, int e){
  if (e == 0) return;
  if (c == 0){
    int iters = 0;
    bool done;
    do {
      int v = (lane < 32) ? ald(&flg[g*32 + lane]) : 0x7fffffff;
      done = __all(v >= e);
      if (!done) __builtin_amdgcn_s_sleep(1);
    } while (!done && ++iters < 262144);
    if (lane == 0) ast(&gready[g], e);
  } else {
    int iters = 0;
    while (ald(&gready[g]) < e && ++iters < 262144)
      __builtin_amdgcn_s_sleep(1);
  }
  asm volatile("" ::: "memory");
}

__global__ __launch_bounds__(64, 1) void gru_layer(
    const bf16* __restrict__ Wh, const bf16* __restrict__ Wl,   // [1536][512] u|r|c
    const float* __restrict__ Xall,                             // [3200][1536]
    float* __restrict__ hf,                                     // [128][512]
    u32* __restrict__ Hp, u32* __restrict__ RHp,                // [128][512] packed
    bf16* __restrict__ Hh, bf16* __restrict__ Hl,               // [3200][512]
    int* __restrict__ flg, int* __restrict__ gready)
{
  __shared__ bf16 WU_h[8192], WU_l[8192];
  __shared__ bf16 WR_h[8192], WR_l[8192];
  __shared__ bf16 WC_h[8192], WC_l[8192];
  const int lane = threadIdx.x & 63;
  const int blk = blockIdx.x;
  const int g = blk >> 5, c = blk & 31;
  const int cl = lane & 15, cq = lane >> 4;

  // stage 16-col weight slices (frag-major: W[kc][lane][8])
  for (int p = 0; p < 16; p++){
    gld_lds16(Wh + (size_t)(c*16 + cl)*512        + p*32 + cq*8, WU_h + p*512);
    gld_lds16(Wl + (size_t)(c*16 + cl)*512        + p*32 + cq*8, WU_l + p*512);
    gld_lds16(Wh + (size_t)(512 + c*16 + cl)*512  + p*32 + cq*8, WR_h + p*512);
    gld_lds16(Wl + (size_t)(512 + c*16 + cl)*512  + p*32 + cq*8, WR_l + p*512);
    gld_lds16(Wh + (size_t)(1024 + c*16 + cl)*512 + p*32 + cq*8, WC_h + p*512);
    gld_lds16(Wl + (size_t)(1024 + c*16 + cl)*512 + p*32 + cq*8, WC_l + p*512);
  }
  __syncthreads();                              // drains gld_lds (vmcnt)

  const int col = c*16 + cl;                    // output col 0..511
  const size_t hbase = (size_t)(g*16 + cl)*512 + cq*8;  // A-frag word base

  float hold[4], ureg[4];
  #pragma unroll
  for (int v=0;v<4;v++) hold[v] = 0.f;

  #pragma unroll 1
  for (int t = 0; t < T_N; t++){
    // ---- phase A: u = sig(h@Wu + Xu); rh = sig(h@Wr + Xr)*h ----
    wait_group(flg, gready, g, c, lane, 2*t);   // h(t-1) ready (no-op t=0)
    u32 hw[16][8];
    #pragma unroll
    for (int kc=0;kc<16;kc++)
      #pragma unroll
      for (int j=0;j<8;j++)
        hw[kc][j] = aldu(&Hp[hbase + kc*32 + j]);
    float xu[4], xr[4];
    #pragma unroll
    for (int v=0;v<4;v++){
      size_t xrow = (size_t)(t*128 + g*16 + cq*4 + v)*1536;
      xu[v] = Xall[xrow + col];
      xr[v] = Xall[xrow + 512 + col];
    }
    f32x4 aU = {0.f,0.f,0.f,0.f}, aR = {0.f,0.f,0.f,0.f};
    #pragma unroll
    for (int kc=0;kc<16;kc++){
      frag8 AH, AL;
      #pragma unroll
      for (int j=0;j<8;j++){
        AH[j] = (short)(hw[kc][j] & 0xffffu);
        AL[j] = (short)(hw[kc][j] >> 16);
      }
      frag8 wuh = *(const frag8*)(WU_h + kc*512 + lane*8);
      frag8 wul = *(const frag8*)(WU_l + kc*512 + lane*8);
      frag8 wrh = *(const frag8*)(WR_h + kc*512 + lane*8);
      frag8 wrl = *(const frag8*)(WR_l + kc*512 + lane*8);
      aU = mfma16(AH, wuh, aU);
      aU = mfma16(AH, wul, aU);
      aU = mfma16(AL, wuh, aU);
      aR = mfma16(AH, wrh, aR);
      aR = mfma16(AH, wrl, aR);
      aR = mfma16(AL, wrh, aR);
    }
    #pragma unroll
    for (int v=0;v<4;v++){
      float u = sigmoidf_(aU[v] + xu[v]);
      ureg[v] = u;
      float rh = sigmoidf_(aR[v] + xr[v]) * hold[v];
      bf16 hi = f2bf(rh); bf16 lo = f2bf(rh - bf2f(hi));
      u32 w = (u32)*(unsigned short*)&hi | ((u32)*(unsigned short*)&lo << 16);
      astu(&RHp[(size_t)(g*16 + cq*4 + v)*512 + col], w);
    }
    asm volatile("s_waitcnt vmcnt(0)" ::: "memory");
    ast(&flg[blk], 2*t + 1);

    // ---- phase B: h' = u*h + (1-u)*tanh((r*h)@Wc + Xc) ----
    wait_group(flg, gready, g, c, lane, 2*t + 1);
    u32 rw[16][8];
    #pragma unroll
    for (int kc=0;kc<16;kc++)
      #pragma unroll
      for (int j=0;j<8;j++)
        rw[kc][j] = aldu(&RHp[hbase + kc*32 + j]);
    float xc[4];
    #pragma unroll
    for (int v=0;v<4;v++){
      size_t xrow = (size_t)(t*128 + g*16 + cq*4 + v)*1536;
      xc[v] = Xall[xrow + 1024 + col];
    }
    f32x4 aC = {0.f,0.f,0.f,0.f};
    #pragma unroll
    for (int kc=0;kc<16;kc++){
      frag8 AH, AL;
      #pragma unroll
      for (int j=0;j<8;j++){
        AH[j] = (short)(rw[kc][j] & 0xffffu);
        AL[j] = (short)(rw[kc][j] >> 16);
      }
      frag8 wch = *(const frag8*)(WC_h + kc*512 + lane*8);
      frag8 wcl = *(const frag8*)(WC_l + kc*512 + lane*8);
      aC = mfma16(AH, wch, aC);
      aC = mfma16(AH, wcl, aC);
      aC = mfma16(AL, wch, aC);
    }
    #pragma unroll
    for (int v=0;v<4;v++){
      int grow = g*16 + cq*4 + v;
      float hh = tanhf_(aC[v] + xc[v]);
      float u = ureg[v];
      float hn = u*hold[v] + (1.f - u)*hh;
      hold[v] = hn;
      bf16 hi = f2bf(hn); bf16 lo = f2bf(hn - bf2f(hi));
      u32 w = (u32)*(unsigned short*)&hi | ((u32)*(unsigned short*)&lo << 16);
      astu(&Hp[(size_t)grow*512 + col], w);
      size_t ot = (size_t)(t*128 + grow)*512 + col;
      Hh[ot] = hi; Hl[ot] = lo;
      if (t == T_N-1) hf[(size_t)grow*512 + col] = hn;
    }
    asm volatile("s_waitcnt vmcnt(0)" ::: "memory");
    ast(&flg[blk], 2*t + 2);
  }
}

// ---------------- hidden output (f32) ----------------
__global__ __launch_bounds__(256) void hidden_out(const float* __restrict__ h0f,
    const float* __restrict__ h1f, float* __restrict__ out){
  int i = blockIdx.x*256 + threadIdx.x;
  out[i] = (i < 65536) ? h0f[i] : h1f[i - 65536];
}

// ---------------- host ----------------
extern "C" void kernel_launch(void* const* d_in, const int* in_sizes, int n_in,
                              void* d_out, int out_size, void* d_ws, size_t ws_size,
                              hipStream_t stream)
{
  const void* tokens = d_in[0];
  const void* cnn  = d_in[1];
  const void* emb  = d_in[2];
  const void* Win  = d_in[3];
  const void* bin  = d_in[4];
  const void* Wout = d_in[5];
  const void* bout = d_in[6];
  const void* Wu0  = d_in[7];
  const void* bu0  = d_in[8];
  const void* Wr0  = d_in[9];
  const void* br0  = d_in[10];
  const void* Wc0  = d_in[11];
  const void* bc0  = d_in[12];
  const void* Wu1  = d_in[13];
  const void* bu1  = d_in[14];
  const void* Wr1  = d_in[15];
  const void* br1  = d_in[16];
  const void* Wc1  = d_in[17];
  const void* bc1  = d_in[18];

  char* wp = (char*)d_ws;
  auto alloc = [&](size_t bytes) -> char* {
    char* r = wp; wp += (bytes + 255) & ~(size_t)255; return r;
  };
  auto B2 = [](size_t n){ return n*2; };
  bf16* WinTh  = (bf16*)alloc(B2(512*2048)); bf16* WinTl  = (bf16*)alloc(B2(512*2048));
  bf16* WoutTh = (bf16*)alloc(B2((size_t)10112*512));
  bf16* W0xTh = (bf16*)alloc(B2((size_t)1536*1024)); bf16* W0xTl = (bf16*)alloc(B2((size_t)1536*1024));
  bf16* W0hTh = (bf16*)alloc(B2((size_t)1536*512));  bf16* W0hTl = (bf16*)alloc(B2((size_t)1536*512));
  bf16* W1xTh = (bf16*)alloc(B2((size_t)1536*512));  bf16* W1xTl = (bf16*)alloc(B2((size_t)1536*512));
  bf16* W1hTh = (bf16*)alloc(B2((size_t)1536*512));  bf16* W1hTl = (bf16*)alloc(B2((size_t)1536*512));
  bf16* embH = (bf16*)alloc(B2((size_t)10000*512));
  bf16* embL = (bf16*)alloc(B2((size_t)10000*512));
  bf16* cnnH = (bf16*)alloc(B2(128*2048)); bf16* cnnL = (bf16*)alloc(B2(128*2048));
  bf16* pH   = (bf16*)alloc(B2(128*512)); bf16* pL = (bf16*)alloc(B2(128*512));
  bf16* X0AH = (bf16*)alloc(B2((size_t)3200*1024)); bf16* X0AL = (bf16*)alloc(B2((size_t)3200*1024));
  float* Xall = (float*)alloc((size_t)3200*1536*4);
  bf16* H0h = (bf16*)alloc(B2((size_t)3200*512)); bf16* H0l = (bf16*)alloc(B2((size_t)3200*512));
  bf16* H1h = (bf16*)alloc(B2((size_t)3200*512)); bf16* H1l = (bf16*)alloc(B2((size_t)3200*512));
  float* binF = (float*)alloc(512*4);
  float* boutF = (float*)alloc(10000*4);
  float* b0all = (float*)alloc(1536*4);
  float* b1all = (float*)alloc(1536*4);
  float* h0f = (float*)alloc(65536*4); float* h1f = (float*)alloc(65536*4);
  u32* Hp0  = (u32*)alloc(65536*4); u32* RHp0 = (u32*)alloc(65536*4);
  u32* Hp1  = (u32*)alloc(65536*4); u32* RHp1 = (u32*)alloc(65536*4);
  int* flags = (int*)alloc(256);
  int* bar = (int*)alloc(2304);                 // flg0[256] gr0[8] flg1[256] gr1[8]
  int* flg0 = bar;          int* gr0 = bar + 256;
  int* flg1 = bar + 264;    int* gr1 = bar + 520;

  detect_kernel<<<1, 256, 0, stream>>>((const unsigned short*)emb, (const int*)tokens, flags);
  cvt_split<<<5000, 256, 0, stream>>>(emb, embH, embL, 5120000, flags);
  cvt_split<<<256, 256, 0, stream>>>(cnn, cnnH, cnnL, 262144, flags);
  CDs cds;
  cds.d[0] = {bin,  binF,  512};
  cds.d[1] = {bout, boutF, 10000};
  cds.d[2] = {bu0,  b0all + 0,    512};
  cds.d[3] = {br0,  b0all + 512,  512};
  cds.d[4] = {bc0,  b0all + 1024, 512};
  cds.d[5] = {bu1,  b1all + 0,    512};
  cds.d[6] = {br1,  b1all + 512,  512};
  cds.d[7] = {bc1,  b1all + 1024, 512};
  cvt_f32_batch<<<dim3(40, 8), 256, 0, stream>>>(cds, flags);

  TDs tds;
  tds.d[0]  = {Win,  WinTh, WinTl, 0, 2048, 512, 512, 512};
  tds.d[1]  = {Wout, WoutTh, nullptr, 0, 512, 10112, 10000, 10000};
  tds.d[2]  = {Wu0, W0xTh,               W0xTl,               0,    1024, 512, 512, 512};
  tds.d[3]  = {Wr0, W0xTh + 512*1024,    W0xTl + 512*1024,    0,    1024, 512, 512, 512};
  tds.d[4]  = {Wc0, W0xTh + 1024*1024,   W0xTl + 1024*1024,   512,  1024, 512, 512, 512};
  tds.d[5]  = {Wu0, W0hTh,               W0hTl,               1024, 512,  512, 512, 512};
  tds.d[6]  = {Wr0, W0hTh + 512*512,     W0hTl + 512*512,     1024, 512,  512, 512, 512};
  tds.d[7]  = {Wc0, W0hTh + 1024*512,    W0hTl + 1024*512,    0,    512,  512, 512, 512};
  tds.d[8]  = {Wu1, W1xTh,               W1xTl,               0,    512,  512, 512, 512};
  tds.d[9]  = {Wr1, W1xTh + 512*512,     W1xTl + 512*512,     0,    512,  512, 512, 512};
  tds.d[10] = {Wc1, W1xTh + 1024*512,    W1xTl + 1024*512,    512,  512,  512, 512, 512};
  tds.d[11] = {Wu1, W1hTh,               W1hTl,               512,  512,  512, 512, 512};
  tds.d[12] = {Wr1, W1hTh + 512*512,     W1hTl + 512*512,     512,  512,  512, 512, 512};
  tds.d[13] = {Wc1, W1hTh + 1024*512,    W1hTl + 1024*512,    0,    512,  512, 512, 512};
  transpose_many<<<dim3(5056, 14), 256, 0, stream>>>(tds, flags);

  init_zero<<<256, 256, 0, stream>>>(h0f, h1f, Hp0, Hp1, bar);

  gemm_split<1><<<dim3(4, 1), 256, 0, stream>>>(
      cnnH, cnnL, WinTh, WinTl, binF, nullptr, pH, pL, 2048, 512);
  build_x0a<<<3200, 256, 0, stream>>>((const int*)tokens, embH, embL, pH, pL, X0AH, X0AL, flags);
  gemm_split<0><<<dim3(12, 25), 256, 0, stream>>>(
      X0AH, X0AL, W0xTh, W0xTl, b0all, Xall, nullptr, nullptr, 1024, 1536);

  gru_layer<<<256, 64, 0, stream>>>(W0hTh, W0hTl, Xall, h0f, Hp0, RHp0,
                                    H0h, H0l, flg0, gr0);

  gemm_split<0><<<dim3(12, 25), 256, 0, stream>>>(
      H0h, H0l, W1xTh, W1xTl, b1all, Xall, nullptr, nullptr, 512, 1536);

  gru_layer<<<256, 64, 0, stream>>>(W1hTh, W1hTl, Xall, h1f, Hp1, RHp1,
                                    H1h, H1l, flg1, gr1);

  float* out = (float*)d_out;
  gemm_logits<<<dim3(79, 25), 256, 0, stream>>>(H1h, WoutTh, boutF, out, 512, 10000);
  hidden_out<<<512, 256, 0, stream>>>(h0f, h1f, out + 32000000);
}